// Round 4
// baseline (240.532 us; speedup 1.0000x reference)
//
#include <hip/hip_runtime.h>
#include <cfloat>

#define DIM 2048
#define NE  64

typedef _Float16 half8 __attribute__((ext_vector_type(8)));
typedef float    f32x4 __attribute__((ext_vector_type(4)));

struct Split { _Float16 hi, lo; };

// Branchless split of a PRE-SCALED fp32 value: xs ≈ hi + lo/2048 in fp16 pair.
// Callers scale inputs by an exact power of two so |xs| is far from the fp16
// denormal range (A: x*64, |xs|<~350; B: w*1024, |xs|<22.7) — strictly more
// accurate than the old denormal-clamp branch, and cheaper.
__device__ __forceinline__ Split split2(float xs) {
    Split r;
    r.hi = (_Float16)xs;             // v_cvt_f16_f32 (RTN)
    float h32 = (float)r.hi;
    r.lo = (_Float16)((xs - h32) * 2048.0f);
    return r;
}

// EXPERIMENT (round 3/4): drop the d_ws split-W workspace entirely.
// Evidence: the timed iteration is ~216 µs = 2x 77 µs harness poison-fills of
// the 512 MB workspace + ~60 µs gate kernel. The ws fast path saves no B
// traffic (512 KB/block of split fp16 vs 512 KB/block of raw fp32 W — same
// bytes) and only saves ~190 VALU ops/step on a 15%-busy VALU. If re-poison
// is conditional on workspace use, wall time collapses to the gate kernel.
//
// 1024 blocks x 256 thr (4 waves). Block = 16 tokens; wave w = K-quarter w
// (16 K32-steps). Register pipeline:
//   B: raw fp32 W rows (L2-resident 512 KB), double-buffered 1 step ahead,
//      split to fp16 hi/lo at consume time.
//   A: x stream (L3-resident across iterations), depth-2 prefetch, 3-slot ring.
__launch_bounds__(256, 2)
__global__ void gate_mfma_kernel(const float* __restrict__ x,
                                 const float* __restrict__ W,
                                 const float* __restrict__ b,
                                 float* __restrict__ out)
{
    __shared__ float sgrid[4][16][68];   // [k-quarter][token][expert], padded

    const int tid  = threadIdx.x;
    const int lane = tid & 63;
    const int wave = tid >> 6;           // k-quarter 0..3
    const int tokb = blockIdx.x * 16;
    const int row  = tokb + (lane & 15);

    const float* aptr = x + (size_t)row * DIM + wave * 512 + (lane >> 4) * 8;
    // B: lane l of chunk (s,nt) holds W[nt*16 + (l&15)][wave*512 + s*32 + (l>>4)*8 + 0..7]
    const float* wptr = W + (size_t)(lane & 15) * DIM + wave * 512 + (lane >> 4) * 8;

    f32x4 acch[4], accc[4];
    #pragma unroll
    for (int nt = 0; nt < 4; ++nt) {
        acch[nt] = (f32x4){0.f, 0.f, 0.f, 0.f};
        accc[nt] = (f32x4){0.f, 0.f, 0.f, 0.f};
    }

    f32x4 Bf0[2][4], Bf1[2][4];          // B fp32 double buffer: [buf][nt], 8 floats each
    f32x4 A0[3], A1[3];                  // depth-2 prefetch ring on A

    // ---- preload: B step 0; A steps 0..1 ----
    #pragma unroll
    for (int nt = 0; nt < 4; ++nt) {
        const float* wp = wptr + nt * 16 * DIM;
        Bf0[0][nt] = *(const f32x4*)(wp);
        Bf1[0][nt] = *(const f32x4*)(wp + 4);
    }
    A0[0] = *(const f32x4*)(aptr);
    A1[0] = *(const f32x4*)(aptr + 4);
    A0[1] = *(const f32x4*)(aptr + 32);
    A1[1] = *(const f32x4*)(aptr + 36);

    #pragma unroll
    for (int s = 0; s < 16; ++s) {
        const int cur = s & 1, nxt = cur ^ 1;
        const int ca  = s % 3;           // static after full unroll

        // ---- issue next B (1 ahead, L2 ~200cyc) and A (2 ahead, L3 ~600cyc) ----
        if (s + 1 < 16) {
            #pragma unroll
            for (int nt = 0; nt < 4; ++nt) {
                const float* wp = wptr + nt * 16 * DIM + (s + 1) * 32;
                Bf0[nxt][nt] = *(const f32x4*)(wp);
                Bf1[nxt][nt] = *(const f32x4*)(wp + 4);
            }
        }
        if (s + 2 < 16) {
            const int na = (s + 2) % 3;
            A0[na] = *(const f32x4*)(aptr + (s + 2) * 32);
            A1[na] = *(const f32x4*)(aptr + (s + 2) * 32 + 4);
        }

        // ---- split current A (scaled x64) ----
        half8 Ah, Al;
        #pragma unroll
        for (int j = 0; j < 4; ++j) {
            Split s0 = split2(A0[ca][j] * 64.0f);
            Ah[j] = s0.hi; Al[j] = s0.lo;
            Split s1 = split2(A1[ca][j] * 64.0f);
            Ah[4 + j] = s1.hi; Al[4 + j] = s1.lo;
        }

        // ---- per-nt: split B (scaled x1024) + 3 MFMAs ----
        #pragma unroll
        for (int nt = 0; nt < 4; ++nt) {
            half8 Bh, Bl;
            #pragma unroll
            for (int j = 0; j < 4; ++j) {
                Split s0 = split2(Bf0[cur][nt][j] * 1024.0f);
                Bh[j] = s0.hi; Bl[j] = s0.lo;
                Split s1 = split2(Bf1[cur][nt][j] * 1024.0f);
                Bh[4 + j] = s1.hi; Bl[4 + j] = s1.lo;
            }
            acch[nt] = __builtin_amdgcn_mfma_f32_16x16x32_f16(Ah, Bh, acch[nt], 0, 0, 0);
            accc[nt] = __builtin_amdgcn_mfma_f32_16x16x32_f16(Al, Bh, accc[nt], 0, 0, 0);
            accc[nt] = __builtin_amdgcn_mfma_f32_16x16x32_f16(Ah, Bl, accc[nt], 0, 0, 0);
        }
    }

    // ---- partial scores to LDS: D row=(lane>>4)*4+r (token), col=lane&15 (expert) ----
    // un-scale: A*64, B*1024 → product *65536; cross terms carry an extra /2048
    #pragma unroll
    for (int nt = 0; nt < 4; ++nt)
        #pragma unroll
        for (int r = 0; r < 4; ++r) {
            int tl = (lane >> 4) * 4 + r;
            int e  = nt * 16 + (lane & 15);
            sgrid[wave][tl][e] =
                (acch[nt][r] + accc[nt][r] * (1.0f / 2048.0f)) * (1.0f / 65536.0f);
        }
    __syncthreads();

    // ---- per-token top-2 + renormalized softmax (proven epilogue) ----
    const float bias = b[lane];
    #pragma unroll
    for (int tt = 0; tt < 4; ++tt) {
        const int t = wave * 4 + tt;
        float s = sgrid[0][t][lane] + sgrid[1][t][lane]
                + sgrid[2][t][lane] + sgrid[3][t][lane] + bias;

        float v = s; int i = lane;
        #pragma unroll
        for (int off = 32; off > 0; off >>= 1) {
            float ov = __shfl_xor(v, off, 64);
            int   oi = __shfl_xor(i, off, 64);
            if (ov > v || (ov == v && oi < i)) { v = ov; i = oi; }
        }
        const float m1 = v; const int i1 = i;

        float s2 = (lane == i1) ? -FLT_MAX : s;
        v = s2; i = lane;
        #pragma unroll
        for (int off = 32; off > 0; off >>= 1) {
            float ov = __shfl_xor(v, off, 64);
            int   oi = __shfl_xor(i, off, 64);
            if (ov > v || (ov == v && oi < i)) { v = ov; i = oi; }
        }
        const float m2 = v; const int i2 = i;

        const float e_  = __expf(m2 - m1);
        const float inv = 1.f / (1.f + e_);
        const float outv = (lane == i1) ? inv : ((lane == i2) ? e_ * inv : 0.f);
        out[(size_t)(tokb + t) * NE + lane] = outv;
    }
}

extern "C" void kernel_launch(void* const* d_in, const int* in_sizes, int n_in,
                              void* d_out, int out_size, void* d_ws, size_t ws_size,
                              hipStream_t stream) {
    const float* x = (const float*)d_in[0];
    const float* W = (const float*)d_in[1];
    const float* b = (const float*)d_in[2];
    float* out = (float*)d_out;

    const int n_tokens = in_sizes[0] / DIM;      // 16384
    dim3 grid(n_tokens / 16);                    // 1024 blocks
    dim3 block(256);                             // 4 waves

    // NOTE: d_ws deliberately unused — the 512 MB workspace re-poison fills
    // (2 x ~77 µs per timed iteration) dominated the wall time.
    (void)d_ws; (void)ws_size;
    gate_mfma_kernel<<<grid, block, 0, stream>>>(x, W, b, out);
}

// Round 5
// 222.254 us; speedup vs baseline: 1.0822x; 1.0822x over previous
//
#include <hip/hip_runtime.h>
#include <cfloat>

#define DIM 2048
#define NE  64

typedef _Float16 half8 __attribute__((ext_vector_type(8)));
typedef float    f32x4 __attribute__((ext_vector_type(4)));

struct Split { _Float16 hi, lo; };

// Split fp32 into fp16 hi + fp16 lo where x ≈ hi + lo/2048.
// hi clamped to 0 below fp16-min-normal so no denormal reaches the MFMA.
__device__ __forceinline__ Split split_f32(float x) {
    Split r;
    float h32;
    if (__builtin_fabsf(x) >= 6.103515625e-05f) {
        r.hi = (_Float16)x;          // v_cvt_f16_f32 (RTN)
        h32  = (float)r.hi;
    } else {
        r.hi = (_Float16)0.0f; h32 = 0.0f;
    }
    r.lo = (_Float16)((x - h32) * 2048.0f);
    return r;
}

// Pre-kernel: split W [64][2048] into fragment-ordered fp16 hi/lo in ws.
// hi element index: (sg*4 + nt)*64 + lane ; lo at +16384 (half8 units).
// Lane l of chunk (sg,nt) holds W[nt*16 + (l&15)][sg*32 + (l>>4)*8 + 0..7].
__global__ void wsplit_kernel(const float* __restrict__ W, _Float16* __restrict__ wsb) {
    int t    = blockIdx.x * 256 + threadIdx.x;   // 0..16383
    int lane = t & 63;
    int nt   = (t >> 6) & 3;
    int sg   = t >> 8;                           // k32-step 0..63
    int e    = nt * 16 + (lane & 15);
    int k    = sg * 32 + (lane >> 4) * 8;
    const float* wp = W + (size_t)e * DIM + k;
    half8 hi, lo;
    #pragma unroll
    for (int j = 0; j < 8; ++j) {
        Split s = split_f32(wp[j]);
        hi[j] = s.hi; lo[j] = s.lo;
    }
    ((half8*)wsb)[(size_t)((sg * 4 + nt) * 64 + lane)]         = hi;
    ((half8*)wsb)[(size_t)(16384 + (sg * 4 + nt) * 64 + lane)] = lo;
}

// Main: 1024 blocks x 512 thr (8 waves). Block = 16 tokens; wave w = K-EIGHTH w
// (8 K32-steps). Rationale (r4 post-mortem): all pipes <20% busy, occupancy
// grid-capped at ~13 waves/CU — the kernel is latency-bound with too little
// TLP. 8 waves/block doubles resident waves to the 32/CU cap; per-wave
// register pipeline (B 1-ahead dbuf from L2-resident ws, A depth-2 ring from
// L3-resident x) is unchanged — it was proven latency-neutral in r1/r2.
template <bool USE_WS>
__launch_bounds__(512, 8)
__global__ void gate_mfma_kernel(const float* __restrict__ x,
                                 const float* __restrict__ W,
                                 const float* __restrict__ b,
                                 float* __restrict__ out,
                                 const _Float16* __restrict__ wsb)
{
    __shared__ float sgrid[8][16][68];   // [k-eighth][token][expert], padded

    const int tid  = threadIdx.x;
    const int lane = tid & 63;
    const int wave = tid >> 6;           // k-eighth 0..7
    const int tokb = blockIdx.x * 16;
    const int row  = tokb + (lane & 15);

    const float* aptr = x + (size_t)row * DIM + wave * 256 + (lane >> 4) * 8;
    const half8* wb   = (const half8*)wsb;
    // half8 index for (s, nt): wave*2048 + s*256 + nt*64 + lane  (sg = wave*8+s)
    const int bbase = wave * 2048 + lane;

    f32x4 acch[4], accc[4];
    #pragma unroll
    for (int nt = 0; nt < 4; ++nt) {
        acch[nt] = (f32x4){0.f, 0.f, 0.f, 0.f};
        accc[nt] = (f32x4){0.f, 0.f, 0.f, 0.f};
    }

    half8 Bh[2][4], Bl[2][4];
    f32x4 A0[3], A1[3];                  // depth-2 prefetch ring on A

    // ---- preload: B step 0; A steps 0..1 ----
    if (USE_WS) {
        #pragma unroll
        for (int nt = 0; nt < 4; ++nt) {
            Bh[0][nt] = wb[bbase + nt * 64];
            Bl[0][nt] = wb[16384 + bbase + nt * 64];
        }
    }
    A0[0] = *(const f32x4*)(aptr);
    A1[0] = *(const f32x4*)(aptr + 4);
    A0[1] = *(const f32x4*)(aptr + 32);
    A1[1] = *(const f32x4*)(aptr + 36);

    #pragma unroll
    for (int s = 0; s < 8; ++s) {
        const int cur = s & 1, nxt = cur ^ 1;
        const int ca  = s % 3;           // static after full unroll

        // ---- issue next B (1 ahead) and A (2 ahead) ----
        if (USE_WS && s + 1 < 8) {
            const int o = bbase + (s + 1) * 256;
            #pragma unroll
            for (int nt = 0; nt < 4; ++nt) {
                Bh[nxt][nt] = wb[o + nt * 64];
                Bl[nxt][nt] = wb[16384 + o + nt * 64];
            }
        }
        if (s + 2 < 8) {
            const int na = (s + 2) % 3;
            A0[na] = *(const f32x4*)(aptr + (s + 2) * 32);
            A1[na] = *(const f32x4*)(aptr + (s + 2) * 32 + 4);
        }

        // ---- split current A ----
        half8 Ah, Al;
        #pragma unroll
        for (int j = 0; j < 4; ++j) {
            Split sp = split_f32(A0[ca][j]);
            Ah[j] = sp.hi; Al[j] = sp.lo;
        }
        #pragma unroll
        for (int j = 0; j < 4; ++j) {
            Split sp = split_f32(A1[ca][j]);
            Ah[4 + j] = sp.hi; Al[4 + j] = sp.lo;
        }

        // ---- B for fallback path (no ws): load + split on demand ----
        half8 Bhc[4], Blc[4];
        if (USE_WS) {
            #pragma unroll
            for (int nt = 0; nt < 4; ++nt) { Bhc[nt] = Bh[cur][nt]; Blc[nt] = Bl[cur][nt]; }
        } else {
            const int sg = wave * 8 + s;
            #pragma unroll
            for (int nt = 0; nt < 4; ++nt) {
                const float* wp = W + (size_t)(nt * 16 + (lane & 15)) * DIM
                                    + sg * 32 + (lane >> 4) * 8;
                #pragma unroll
                for (int j = 0; j < 8; ++j) {
                    Split sp = split_f32(wp[j]);
                    Bhc[nt][j] = sp.hi; Blc[nt][j] = sp.lo;
                }
            }
        }

        // ---- 12 MFMAs ----
        #pragma unroll
        for (int nt = 0; nt < 4; ++nt) {
            acch[nt] = __builtin_amdgcn_mfma_f32_16x16x32_f16(Ah, Bhc[nt], acch[nt], 0, 0, 0);
            accc[nt] = __builtin_amdgcn_mfma_f32_16x16x32_f16(Al, Bhc[nt], accc[nt], 0, 0, 0);
            accc[nt] = __builtin_amdgcn_mfma_f32_16x16x32_f16(Ah, Blc[nt], accc[nt], 0, 0, 0);
        }
    }

    // ---- partial scores to LDS: D row=(lane>>4)*4+r (token), col=lane&15 (expert) ----
    #pragma unroll
    for (int nt = 0; nt < 4; ++nt)
        #pragma unroll
        for (int r = 0; r < 4; ++r) {
            int tl = (lane >> 4) * 4 + r;
            int e  = nt * 16 + (lane & 15);
            sgrid[wave][tl][e] = acch[nt][r] + accc[nt][r] * (1.0f / 2048.0f);
        }
    __syncthreads();

    // ---- per-token top-2 + renormalized softmax (proven epilogue) ----
    // 8 waves x 2 tokens each = 16 tokens.
    const float bias = b[lane];
    #pragma unroll
    for (int tt = 0; tt < 2; ++tt) {
        const int t = wave * 2 + tt;
        float s = bias;
        #pragma unroll
        for (int q = 0; q < 8; ++q) s += sgrid[q][t][lane];

        float v = s; int i = lane;
        #pragma unroll
        for (int off = 32; off > 0; off >>= 1) {
            float ov = __shfl_xor(v, off, 64);
            int   oi = __shfl_xor(i, off, 64);
            if (ov > v || (ov == v && oi < i)) { v = ov; i = oi; }
        }
        const float m1 = v; const int i1 = i;

        float s2 = (lane == i1) ? -FLT_MAX : s;
        v = s2; i = lane;
        #pragma unroll
        for (int off = 32; off > 0; off >>= 1) {
            float ov = __shfl_xor(v, off, 64);
            int   oi = __shfl_xor(i, off, 64);
            if (ov > v || (ov == v && oi < i)) { v = ov; i = oi; }
        }
        const float m2 = v; const int i2 = i;

        const float e_  = __expf(m2 - m1);
        const float inv = 1.f / (1.f + e_);
        const float outv = (lane == i1) ? inv : ((lane == i2) ? e_ * inv : 0.f);
        out[(size_t)(tokb + t) * NE + lane] = outv;
    }
}

extern "C" void kernel_launch(void* const* d_in, const int* in_sizes, int n_in,
                              void* d_out, int out_size, void* d_ws, size_t ws_size,
                              hipStream_t stream) {
    const float* x = (const float*)d_in[0];
    const float* W = (const float*)d_in[1];
    const float* b = (const float*)d_in[2];
    float* out = (float*)d_out;

    const int n_tokens = in_sizes[0] / DIM;      // 16384
    dim3 grid(n_tokens / 16);                    // 1024 blocks
    dim3 block(512);                             // 8 waves

    // The 512 MB workspace re-poison fills (~154 µs/iter) are UNCONDITIONAL
    // (measured r4: wall stayed fill-dominated with ws unused), so using the
    // 512 KB split-W fast path costs nothing extra.
    if (ws_size >= 524288) {
        wsplit_kernel<<<dim3(64), dim3(256), 0, stream>>>(W, (_Float16*)d_ws);
        gate_mfma_kernel<true><<<grid, block, 0, stream>>>(x, W, b, out, (const _Float16*)d_ws);
    } else {
        gate_mfma_kernel<false><<<grid, block, 0, stream>>>(x, W, b, out, nullptr);
    }
}

// Round 6
// 211.741 us; speedup vs baseline: 1.1360x; 1.0497x over previous
//
#include <hip/hip_runtime.h>
#include <cfloat>

#define DIM 2048
#define NE  64

typedef _Float16 half8 __attribute__((ext_vector_type(8)));
typedef float    f32x4 __attribute__((ext_vector_type(4)));

struct Split { _Float16 hi, lo; };

// Split fp32 into fp16 hi + fp16 lo where x ≈ hi + lo/2048.
// hi clamped to 0 below fp16-min-normal so no denormal reaches the MFMA.
__device__ __forceinline__ Split split_f32(float x) {
    Split r;
    float h32;
    if (__builtin_fabsf(x) >= 6.103515625e-05f) {
        r.hi = (_Float16)x;          // v_cvt_f16_f32 (RTN)
        h32  = (float)r.hi;
    } else {
        r.hi = (_Float16)0.0f; h32 = 0.0f;
    }
    r.lo = (_Float16)((x - h32) * 2048.0f);
    return r;
}

// Pre-kernel: split W [64][2048] into fragment-ordered fp16 hi/lo in ws.
// hi element index: (sg*4 + nt)*64 + lane ; lo at +16384 (half8 units).
// Lane l of chunk (sg,nt) holds W[nt*16 + (l&15)][sg*32 + (l>>4)*8 + 0..7].
__global__ void wsplit_kernel(const float* __restrict__ W, _Float16* __restrict__ wsb) {
    int t    = blockIdx.x * 256 + threadIdx.x;   // 0..16383
    int lane = t & 63;
    int nt   = (t >> 6) & 3;
    int sg   = t >> 8;                           // k32-step 0..63
    int e    = nt * 16 + (lane & 15);
    int k    = sg * 32 + (lane >> 4) * 8;
    const float* wp = W + (size_t)e * DIM + k;
    half8 hi, lo;
    #pragma unroll
    for (int j = 0; j < 8; ++j) {
        Split s = split_f32(wp[j]);
        hi[j] = s.hi; lo[j] = s.lo;
    }
    ((half8*)wsb)[(size_t)((sg * 4 + nt) * 64 + lane)]         = hi;
    ((half8*)wsb)[(size_t)(16384 + (sg * 4 + nt) * 64 + lane)] = lo;
}

// Main (r6 restructure): 256 blocks x 512 thr (8 waves). Block = 64 TOKENS.
// Wave w = K-eighth w (8 k32-steps) x 4 token-tiles (M=64) x 64 experts.
// Rationale (r5 post-mortem): occupancy doubling was NULL while warm-L3
// replay passes ran the same 80 µs — the kernel is bound by the L3-level
// B re-read stream (536 MB). Reusing each B fragment across 4 M-tiles
// in-register cuts B traffic 4x (536 -> 134 MB; total stream 670 -> 272 MB).
// B is single-buffered (reload hides under the 4-tile A-split VALU block);
// A keeps the proven 1-ahead double slot.
template <bool USE_WS>
__launch_bounds__(512, 2)
__global__ void gate_mfma_kernel(const float* __restrict__ x,
                                 const float* __restrict__ W,
                                 const float* __restrict__ b,
                                 float* __restrict__ out,
                                 const _Float16* __restrict__ wsb)
{
    __shared__ float sgrid[8][64][68];   // [k-eighth][token][expert], padded — 139 KB

    const int tid  = threadIdx.x;
    const int lane = tid & 63;
    const int wave = tid >> 6;           // k-eighth 0..7
    const int tokb = blockIdx.x * 64;

    // A: m-tile m covers tokens tokb + m*16 .. +16; this lane reads row (lane&15)
    const float* aptr = x + (size_t)(tokb + (lane & 15)) * DIM + wave * 256 + (lane >> 4) * 8;
    const half8* wb   = (const half8*)wsb;
    // half8 index for (s, nt): wave*2048 + s*256 + nt*64 + lane  (sg = wave*8+s)
    const int bbase = wave * 2048 + lane;

    f32x4 acch[4][4], accc[4][4];        // [m][nt] — 128 VGPR
    #pragma unroll
    for (int m = 0; m < 4; ++m)
        #pragma unroll
        for (int nt = 0; nt < 4; ++nt) {
            acch[m][nt] = (f32x4){0.f, 0.f, 0.f, 0.f};
            accc[m][nt] = (f32x4){0.f, 0.f, 0.f, 0.f};
        }

    half8 Bh[4], Bl[4];                  // single-buffered B (32 VGPR)
    f32x4 A0[2][4], A1[2][4];            // [slot][m] 1-ahead A (64 VGPR)

    // ---- preload: A step 0; B step 0 ----
    #pragma unroll
    for (int m = 0; m < 4; ++m) {
        const float* ap = aptr + (size_t)m * 16 * DIM;
        A0[0][m] = *(const f32x4*)(ap);
        A1[0][m] = *(const f32x4*)(ap + 4);
    }
    if (USE_WS) {
        #pragma unroll
        for (int nt = 0; nt < 4; ++nt) {
            Bh[nt] = wb[bbase + nt * 64];
            Bl[nt] = wb[16384 + bbase + nt * 64];
        }
    }

    #pragma unroll
    for (int s = 0; s < 8; ++s) {
        const int cur = s & 1, nxt = cur ^ 1;

        // ---- issue next A (1 ahead) ----
        if (s + 1 < 8) {
            #pragma unroll
            for (int m = 0; m < 4; ++m) {
                const float* ap = aptr + (size_t)m * 16 * DIM + (s + 1) * 32;
                A0[nxt][m] = *(const f32x4*)(ap);
                A1[nxt][m] = *(const f32x4*)(ap + 4);
            }
        }

        // ---- split current A, all 4 m-tiles (covers B reload latency) ----
        half8 Ah[4], Al[4];
        #pragma unroll
        for (int m = 0; m < 4; ++m)
            #pragma unroll
            for (int j = 0; j < 4; ++j) {
                Split s0 = split_f32(A0[cur][m][j]);
                Ah[m][j] = s0.hi; Al[m][j] = s0.lo;
                Split s1 = split_f32(A1[cur][m][j]);
                Ah[m][4 + j] = s1.hi; Al[m][4 + j] = s1.lo;
            }

        if (USE_WS) {
            // ---- 48 MFMAs: each B fragment feeds 4 M-tiles ----
            #pragma unroll
            for (int m = 0; m < 4; ++m)
                #pragma unroll
                for (int nt = 0; nt < 4; ++nt) {
                    acch[m][nt] = __builtin_amdgcn_mfma_f32_16x16x32_f16(Ah[m], Bh[nt], acch[m][nt], 0, 0, 0);
                    accc[m][nt] = __builtin_amdgcn_mfma_f32_16x16x32_f16(Al[m], Bh[nt], accc[m][nt], 0, 0, 0);
                    accc[m][nt] = __builtin_amdgcn_mfma_f32_16x16x32_f16(Ah[m], Bl[nt], accc[m][nt], 0, 0, 0);
                }
            // ---- reload B for next step (WAR-ordered after the MFMAs;
            //      latency hides under next step's A-split block) ----
            if (s + 1 < 8) {
                const int o = bbase + (s + 1) * 256;
                #pragma unroll
                for (int nt = 0; nt < 4; ++nt) {
                    Bh[nt] = wb[o + nt * 64];
                    Bl[nt] = wb[16384 + o + nt * 64];
                }
            }
        } else {
            // fallback: split B on demand from raw W
            const int sg = wave * 8 + s;
            #pragma unroll
            for (int nt = 0; nt < 4; ++nt) {
                half8 Bhc, Blc;
                const float* wp = W + (size_t)(nt * 16 + (lane & 15)) * DIM
                                    + sg * 32 + (lane >> 4) * 8;
                #pragma unroll
                for (int j = 0; j < 8; ++j) {
                    Split sp = split_f32(wp[j]);
                    Bhc[j] = sp.hi; Blc[j] = sp.lo;
                }
                #pragma unroll
                for (int m = 0; m < 4; ++m) {
                    acch[m][nt] = __builtin_amdgcn_mfma_f32_16x16x32_f16(Ah[m], Bhc, acch[m][nt], 0, 0, 0);
                    accc[m][nt] = __builtin_amdgcn_mfma_f32_16x16x32_f16(Al[m], Bhc, accc[m][nt], 0, 0, 0);
                    accc[m][nt] = __builtin_amdgcn_mfma_f32_16x16x32_f16(Ah[m], Blc, accc[m][nt], 0, 0, 0);
                }
            }
        }
    }

    // ---- partial scores to LDS: D row=(lane>>4)*4+r (token), col=lane&15 (expert) ----
    #pragma unroll
    for (int m = 0; m < 4; ++m)
        #pragma unroll
        for (int nt = 0; nt < 4; ++nt)
            #pragma unroll
            for (int r = 0; r < 4; ++r) {
                int tl = m * 16 + (lane >> 4) * 4 + r;
                int e  = nt * 16 + (lane & 15);
                sgrid[wave][tl][e] = acch[m][nt][r] + accc[m][nt][r] * (1.0f / 2048.0f);
            }
    __syncthreads();

    // ---- per-token top-2 + renormalized softmax (proven epilogue) ----
    // 8 waves x 8 tokens each = 64 tokens.
    const float bias = b[lane];
    #pragma unroll
    for (int tt = 0; tt < 8; ++tt) {
        const int t = wave * 8 + tt;
        float sv = bias;
        #pragma unroll
        for (int q = 0; q < 8; ++q) sv += sgrid[q][t][lane];

        float v = sv; int i = lane;
        #pragma unroll
        for (int off = 32; off > 0; off >>= 1) {
            float ov = __shfl_xor(v, off, 64);
            int   oi = __shfl_xor(i, off, 64);
            if (ov > v || (ov == v && oi < i)) { v = ov; i = oi; }
        }
        const float m1 = v; const int i1 = i;

        float s2 = (lane == i1) ? -FLT_MAX : sv;
        v = s2; i = lane;
        #pragma unroll
        for (int off = 32; off > 0; off >>= 1) {
            float ov = __shfl_xor(v, off, 64);
            int   oi = __shfl_xor(i, off, 64);
            if (ov > v || (ov == v && oi < i)) { v = ov; i = oi; }
        }
        const float m2 = v; const int i2 = i;

        const float e_  = __expf(m2 - m1);
        const float inv = 1.f / (1.f + e_);
        const float outv = (lane == i1) ? inv : ((lane == i2) ? e_ * inv : 0.f);
        out[(size_t)(tokb + t) * NE + lane] = outv;
    }
}

extern "C" void kernel_launch(void* const* d_in, const int* in_sizes, int n_in,
                              void* d_out, int out_size, void* d_ws, size_t ws_size,
                              hipStream_t stream) {
    const float* x = (const float*)d_in[0];
    const float* W = (const float*)d_in[1];
    const float* b = (const float*)d_in[2];
    float* out = (float*)d_out;

    const int n_tokens = in_sizes[0] / DIM;      // 16384
    dim3 grid(n_tokens / 64);                    // 256 blocks (1 per CU)
    dim3 block(512);                             // 8 waves

    // The 512 MB workspace re-poison fills (~154 µs/iter) are UNCONDITIONAL
    // (measured r4), so the 512 KB split-W fast path costs nothing extra.
    if (ws_size >= 524288) {
        wsplit_kernel<<<dim3(64), dim3(256), 0, stream>>>(W, (_Float16*)d_ws);
        gate_mfma_kernel<true><<<grid, block, 0, stream>>>(x, W, b, out, (const _Float16*)d_ws);
    } else {
        gate_mfma_kernel<false><<<grid, block, 0, stream>>>(x, W, b, out, nullptr);
    }
}